// Round 7
// baseline (218.349 us; speedup 1.0000x reference)
//
#include <hip/hip_runtime.h>
#include <hip/hip_bf16.h>
#include <stdint.h>

#define TOK   4096   // B*L
#define KDIM  1024   // DIN = DPROJ = 1024
#define NDIM  1024
#define NHEAD 8

typedef _Float16 f16;
typedef __attribute__((ext_vector_type(2))) _Float16 h2;
typedef __attribute__((ext_vector_type(8))) _Float16 f16x8;
typedef __attribute__((ext_vector_type(2))) float f32x2;
typedef __attribute__((ext_vector_type(4))) float f32x4;
typedef __attribute__((ext_vector_type(4))) uint u32x4;

#if __has_builtin(__builtin_amdgcn_exp2f)
#define EXP2(x) __builtin_amdgcn_exp2f(x)
#else
#define EXP2(x) exp2f(x)
#endif

__device__ __forceinline__ void gload_lds16(const void* g, void* l) {
    __builtin_amdgcn_global_load_lds(
        (const __attribute__((address_space(1))) void*)g,
        (__attribute__((address_space(3))) void*)l, 16, 0, 0);
}

// Projection-column permutation: reference col c = d*16 + h*2 + e  ->
// packed col c' = h*128 + d*2 + e  (per-(token,head) k/v contiguous).
// perm(c)    = ((c>>1)&7)*128 + (c>>4)*2 + (c&1)
// invperm(c')= ((c'>>1)&63)*16 + (c'>>7)*2 + (c'&1)

// ---------------- fp32 -> fp16 conversion / permutation pre-pass ----------------
struct CvtArgs {
    const float* src[7];
    void*        dst[7];
    int          n4[7];    // float4 count
    int          type[7];  // 0 plain, 1 W row-perm, 2 Wo col-perm
};

__global__ __launch_bounds__(256) void cvt_kernel(CvtArgs a) {
    const int seg = blockIdx.y;
    const int type = a.type[seg];
    const float4* s = (const float4*)a.src[seg];
    const int n4 = a.n4[seg];
    const int stride = gridDim.x * blockDim.x;
    for (int i = blockIdx.x * blockDim.x + threadIdx.x; i < n4; i += stride) {
        float4 v = s[i];
        if (type == 0) {
            f16* d = (f16*)a.dst[seg];
            union { f16 h[4]; uint2 u; } o;
            o.h[0] = (f16)v.x; o.h[1] = (f16)v.y; o.h[2] = (f16)v.z; o.h[3] = (f16)v.w;
            *(uint2*)(d + (size_t)i * 4) = o.u;
        } else if (type == 1) {
            // W[r][*] -> Wh[perm(r)][*]
            f16* d = (f16*)a.dst[seg];
            const int r = i >> 8, c = (i & 255) * 4;
            const int rp = ((r >> 1) & 7) * 128 + (r >> 4) * 2 + (r & 1);
            union { f16 h[4]; uint2 u; } o;
            o.h[0] = (f16)v.x; o.h[1] = (f16)v.y; o.h[2] = (f16)v.z; o.h[3] = (f16)v.w;
            *(uint2*)(d + (size_t)rp * 1024 + c) = o.u;
        } else {
            // Wo[r][c] -> Woh[r][perm(c)]
            f16* d = (f16*)a.dst[seg];
            const int r = i >> 8, c = (i & 255) * 4;
            const int p0 = ((c >> 1) & 7) * 128 + (c >> 4) * 2;
            const int p1 = (((c + 2) >> 1) & 7) * 128 + ((c + 2) >> 4) * 2;
            union { f16 h[2]; uint u; } u01, u23;
            u01.h[0] = (f16)v.x; u01.h[1] = (f16)v.y;
            u23.h[0] = (f16)v.z; u23.h[1] = (f16)v.w;
            *(uint*)(d + (size_t)r * 1024 + p0) = u01.u;
            *(uint*)(d + (size_t)r * 1024 + p1) = u23.u;
        }
    }
}

// ---------------- GEMM: C = A(M x K) * B(N x K)^T + bias ----------------
// 128x128 tile, BK=64, 8 waves (2M x 4N), 512 thr. Double-buffered LDS (64KB)
// + counted vmcnt(4) + both-sides XOR swizzle (conflicts measured 0 in r5).
struct GemmArgs {
    const f16*   A[3];
    const f16*   B[3];
    const float* bias[3];
    void*        C[3];
};

#define VM_WAIT4 asm volatile("s_waitcnt vmcnt(4)" ::: "memory")
#define VM_WAIT0 asm volatile("s_waitcnt vmcnt(0)" ::: "memory")

// OUTMODE 0 = QKV: f16 out + inv-perm bias; z==2 (V) writes f32.
// OUTMODE 1 = final: f32 out, direct bias.
template<int OUTMODE>
__global__ __launch_bounds__(512) void gemm_bt_kernel(GemmArgs ga) {
    constexpr int K = KDIM, N = NDIM;
    constexpr int NT = K / 64;           // 16 K-steps
    const f16*   A    = ga.A[blockIdx.z];
    const f16*   B    = ga.B[blockIdx.z];
    const float* bias = ga.bias[blockIdx.z];

    __shared__ f16 sm[2 * (128 * 64 + 128 * 64)];   // 64 KB

    const int tid  = threadIdx.x;
    const int wave = tid >> 6, lane = tid & 63;
    const int wm = wave >> 2, wn = wave & 3;      // 2M x 4N
    const int bm = blockIdx.x * 128, bn = blockIdx.y * 128;
    const int lrow = lane & 15, kgrp = lane >> 4;

    f32x4 acc[4][2] = {};

    const int srow = tid >> 3;
    const int colL = (tid & 7) << 3;                               // linear LDS col
    const int colG = (((tid & 7) ^ (srow & 7)) << 3);              // pre-swizzled global col

    auto stage = [&](int buf, int kt) {
        f16* As = sm + buf * (128 * 64 + 128 * 64);
        f16* Bs = As + 128 * 64;
        #pragma unroll
        for (int i = 0; i < 2; ++i) {
            const int row = srow + i * 64;
            gload_lds16(A + (size_t)(bm + row) * K + kt + colG, As + row * 64 + colL);
        }
        #pragma unroll
        for (int i = 0; i < 2; ++i) {
            const int row = srow + i * 64;
            gload_lds16(B + (size_t)(bn + row) * K + kt + colG, Bs + row * 64 + colL);
        }
    };

    stage(0, 0);

    const int swz = (lrow & 7) << 3;

    for (int it = 0; it < NT; ++it) {
        const int cur = it & 1;
        if (it + 1 < NT) {
            stage(cur ^ 1, (it + 1) * 64);
            VM_WAIT4;
        } else {
            VM_WAIT0;
        }
        __builtin_amdgcn_s_barrier();
        __builtin_amdgcn_sched_barrier(0);

        const f16* As = sm + cur * (128 * 64 + 128 * 64);
        const f16* Bs = As + 128 * 64;
        #pragma unroll
        for (int kk = 0; kk < 2; ++kk) {
            f16x8 af[4], bf[2];
            const int kcol = (kk * 32 + kgrp * 8) ^ swz;
            #pragma unroll
            for (int mi = 0; mi < 4; ++mi)
                af[mi] = *(const f16x8*)(As + (wm * 64 + mi * 16 + lrow) * 64 + kcol);
            #pragma unroll
            for (int ni = 0; ni < 2; ++ni)
                bf[ni] = *(const f16x8*)(Bs + (wn * 32 + ni * 16 + lrow) * 64 + kcol);
            #pragma unroll
            for (int mi = 0; mi < 4; ++mi)
                #pragma unroll
                for (int ni = 0; ni < 2; ++ni)
                    acc[mi][ni] = __builtin_amdgcn_mfma_f32_16x16x32_f16(af[mi], bf[ni], acc[mi][ni], 0, 0, 0);
        }
        __builtin_amdgcn_s_barrier();
    }

    // C/D layout: col = lane&15, row = (lane>>4)*4 + reg  [verified m89/m91]
    const int rbase = kgrp * 4;
    #pragma unroll
    for (int mi = 0; mi < 4; ++mi) {
        #pragma unroll
        for (int ni = 0; ni < 2; ++ni) {
            const int col = bn + wn * 32 + ni * 16 + lrow;
            const int bidx = (OUTMODE == 0)
                ? (((col >> 1) & 63) * 16 + (col >> 7) * 2 + (col & 1))  // invperm
                : col;
            const float bv = bias[bidx];
            #pragma unroll
            for (int r = 0; r < 4; ++r) {
                const int row = bm + wm * 64 + mi * 16 + rbase + r;
                const float v = acc[mi][ni][r] + bv;
                if constexpr (OUTMODE == 0) {
                    if (blockIdx.z == 2)   // V projection -> f32 (attn reads it cvt-free)
                        ((float*)ga.C[2])[(size_t)row * N + col] = v;
                    else
                        ((f16*)ga.C[blockIdx.z])[(size_t)row * N + col] = (f16)v;
                } else {
                    ((float*)ga.C[blockIdx.z])[(size_t)row * N + col] = v;
                }
            }
        }
    }
}

// ---------------- attention over d_keys axis, zero-LDS ----------------
// Layout [token][head][d]: per-(token,head) k = 64 uints (f16 pairs), v = 64
// float2. One wave per task; k/v wave-uniform broadcast loads; inner loop
// ~4 issue slots/iter: v_dot2_f32_f16, raw v_exp_f32, add, v_pk_fma_f32.
__global__ __launch_bounds__(256) void attn_kernel(const f16* qp, const f16* kp,
                                                   const float* vp, f16* ao) {
    const int tid = threadIdx.x, wave = tid >> 6, lane = tid & 63;
    const int task = blockIdx.x * 4 + wave;       // token*8 + head
    const size_t base = (size_t)task * 64;        // pair index
    const float SCALE = 0.70710678118f * 1.44269504089f;  // 1/sqrt(2)*log2(e)

    union U2 { uint u; h2 h; f16 s[2]; };
    U2 qu; qu.u = ((const uint*)qp)[base + lane];
    const float q0 = (float)qu.s[0] * SCALE, q1 = (float)qu.s[1] * SCALE;
#if __has_builtin(__builtin_amdgcn_fdot2)
    h2 qs; qs[0] = (f16)q0; qs[1] = (f16)q1;
#endif

    const u32x4* kb = (const u32x4*)((const uint*)kp + base);
    const f32x4* vb = (const f32x4*)(vp + base * 2);

    f32x2 o01 = {0.f, 0.f};
    float sum0 = 0.f, sum1 = 0.f;
    #pragma unroll
    for (int g = 0; g < 4; ++g) {
        u32x4 kr[4];   // 16 k-pairs
        f32x4 vr[8];   // 16 v float2s
        #pragma unroll
        for (int i = 0; i < 4; ++i) kr[i] = kb[g * 4 + i];
        #pragma unroll
        for (int i = 0; i < 8; ++i) vr[i] = vb[g * 8 + i];
        #pragma unroll
        for (int s = 0; s < 16; ++s) {
            U2 ku; ku.u = kr[s >> 2][s & 3];
#if __has_builtin(__builtin_amdgcn_fdot2)
            const float sc = __builtin_amdgcn_fdot2(qs, ku.h, 0.0f, false);
#else
            const float sc = fmaf(q0, (float)ku.s[0], q1 * (float)ku.s[1]);
#endif
            const float p = EXP2(sc);
            if (s & 1) sum1 += p; else sum0 += p;
            const f32x2 v2 = {vr[s >> 1][(s & 1) << 1], vr[s >> 1][((s & 1) << 1) + 1]};
            o01 = __builtin_elementwise_fma((f32x2){p, p}, v2, o01);
        }
    }
    const float inv = __builtin_amdgcn_rcpf(sum0 + sum1);
    U2 o;
    o.s[0] = (f16)(o01.x * inv);
    o.s[1] = (f16)(o01.y * inv);
    ((uint*)ao)[base + lane] = o.u;
}

// ---------------- launch ----------------
extern "C" void kernel_launch(void* const* d_in, const int* in_sizes, int n_in,
                              void* d_out, int out_size, void* d_ws, size_t ws_size,
                              hipStream_t stream) {
    const float* queries = (const float*)d_in[0];
    const float* keys    = (const float*)d_in[1];
    const float* values  = (const float*)d_in[2];
    const float* Wq = (const float*)d_in[3];
    const float* bq = (const float*)d_in[4];
    const float* Wk = (const float*)d_in[5];
    const float* bk = (const float*)d_in[6];
    const float* Wv = (const float*)d_in[7];
    const float* bv = (const float*)d_in[8];
    const float* Wo = (const float*)d_in[9];
    const float* bo = (const float*)d_in[10];

    char* ws = (char*)d_ws;
    const size_t MB = 1024 * 1024;
    f16*   Xq   = (f16*)(ws + 0 * MB);    // 4096x1024 f16 = 8 MB
    f16*   Xk   = (f16*)(ws + 8 * MB);
    f16*   Xv   = (f16*)(ws + 16 * MB);
    f16*   Wqh  = (f16*)(ws + 24 * MB);   // row-permuted, 2 MB
    f16*   Wkh  = (f16*)(ws + 26 * MB);
    f16*   Wvh  = (f16*)(ws + 28 * MB);
    f16*   Woh  = (f16*)(ws + 30 * MB);   // col-permuted
    f16*   qp   = (f16*)(ws + 32 * MB);   // [token][head][d] packed, 8 MB
    f16*   kp   = (f16*)(ws + 40 * MB);   // 8 MB
    float* vp32 = (float*)(ws + 48 * MB); // V in f32, 16 MB
    f16*   ao   = (f16*)(ws + 64 * MB);   // 8 MB (total 72 MB)

    CvtArgs ca;
    ca.src[0] = queries; ca.dst[0] = Xq;  ca.n4[0] = TOK * KDIM / 4;  ca.type[0] = 0;
    ca.src[1] = keys;    ca.dst[1] = Xk;  ca.n4[1] = TOK * KDIM / 4;  ca.type[1] = 0;
    ca.src[2] = values;  ca.dst[2] = Xv;  ca.n4[2] = TOK * KDIM / 4;  ca.type[2] = 0;
    ca.src[3] = Wq;      ca.dst[3] = Wqh; ca.n4[3] = NDIM * KDIM / 4; ca.type[3] = 1;
    ca.src[4] = Wk;      ca.dst[4] = Wkh; ca.n4[4] = NDIM * KDIM / 4; ca.type[4] = 1;
    ca.src[5] = Wv;      ca.dst[5] = Wvh; ca.n4[5] = NDIM * KDIM / 4; ca.type[5] = 1;
    ca.src[6] = Wo;      ca.dst[6] = Woh; ca.n4[6] = NDIM * KDIM / 4; ca.type[6] = 2;
    cvt_kernel<<<dim3(256, 7), 256, 0, stream>>>(ca);

    GemmArgs g1;
    g1.A[0] = Xq;  g1.A[1] = Xk;  g1.A[2] = Xv;
    g1.B[0] = Wqh; g1.B[1] = Wkh; g1.B[2] = Wvh;
    g1.bias[0] = bq; g1.bias[1] = bk; g1.bias[2] = bv;
    g1.C[0] = qp; g1.C[1] = kp; g1.C[2] = vp32;
    gemm_bt_kernel<0><<<dim3(32, 8, 3), 512, 0, stream>>>(g1);

    attn_kernel<<<TOK * NHEAD / 4, 256, 0, stream>>>(qp, kp, vp32, ao);

    GemmArgs g2;
    g2.A[0] = ao; g2.B[0] = Woh; g2.bias[0] = bo; g2.C[0] = d_out;
    g2.A[1] = ao; g2.B[1] = Woh; g2.bias[1] = bo; g2.C[1] = d_out;  // unused slots
    g2.A[2] = ao; g2.B[2] = Woh; g2.bias[2] = bo; g2.C[2] = d_out;
    gemm_bt_kernel<1><<<dim3(32, 8, 1), 512, 0, stream>>>(g2);
}

// Round 8
// 192.623 us; speedup vs baseline: 1.1336x; 1.1336x over previous
//
#include <hip/hip_runtime.h>
#include <hip/hip_bf16.h>
#include <stdint.h>

#define TOK   4096   // B*L
#define KDIM  1024   // DIN = DPROJ = 1024
#define NDIM  1024
#define NHEAD 8

typedef _Float16 f16;
typedef __attribute__((ext_vector_type(2))) _Float16 h2;
typedef __attribute__((ext_vector_type(8))) _Float16 f16x8;
typedef __attribute__((ext_vector_type(2))) float f32x2;
typedef __attribute__((ext_vector_type(4))) float f32x4;
typedef __attribute__((ext_vector_type(4))) uint u32x4;

#if __has_builtin(__builtin_amdgcn_exp2f)
#define EXP2(x) __builtin_amdgcn_exp2f(x)
#else
#define EXP2(x) exp2f(x)
#endif

__device__ __forceinline__ void gload_lds16(const void* g, void* l) {
    __builtin_amdgcn_global_load_lds(
        (const __attribute__((address_space(1))) void*)g,
        (__attribute__((address_space(3))) void*)l, 16, 0, 0);
}

// Projection-column permutation: reference col c = d*16 + h*2 + e  ->
// packed col c' = h*128 + d*2 + e  (per-(token,head) k/v contiguous).
// perm(c)    = ((c>>1)&7)*128 + (c>>4)*2 + (c&1)
// invperm(c')= ((c'>>1)&63)*16 + (c'>>7)*2 + (c'&1)

// ---------------- fp32 -> fp16 conversion / permutation pre-pass ----------------
struct CvtArgs {
    const float* src[7];
    void*        dst[7];
    int          n4[7];    // float4 count
    int          type[7];  // 0 plain, 1 W row-perm, 2 Wo col-perm
};

__global__ __launch_bounds__(256) void cvt_kernel(CvtArgs a) {
    const int seg = blockIdx.y;
    const int type = a.type[seg];
    const float4* s = (const float4*)a.src[seg];
    const int n4 = a.n4[seg];
    const int stride = gridDim.x * blockDim.x;
    for (int i = blockIdx.x * blockDim.x + threadIdx.x; i < n4; i += stride) {
        float4 v = s[i];
        if (type == 0) {
            f16* d = (f16*)a.dst[seg];
            union { f16 h[4]; uint2 u; } o;
            o.h[0] = (f16)v.x; o.h[1] = (f16)v.y; o.h[2] = (f16)v.z; o.h[3] = (f16)v.w;
            *(uint2*)(d + (size_t)i * 4) = o.u;
        } else if (type == 1) {
            // W[r][*] -> Wh[perm(r)][*]
            f16* d = (f16*)a.dst[seg];
            const int r = i >> 8, c = (i & 255) * 4;
            const int rp = ((r >> 1) & 7) * 128 + (r >> 4) * 2 + (r & 1);
            union { f16 h[4]; uint2 u; } o;
            o.h[0] = (f16)v.x; o.h[1] = (f16)v.y; o.h[2] = (f16)v.z; o.h[3] = (f16)v.w;
            *(uint2*)(d + (size_t)rp * 1024 + c) = o.u;
        } else {
            // Wo[r][c] -> Woh[r][perm(c)]
            f16* d = (f16*)a.dst[seg];
            const int r = i >> 8, c = (i & 255) * 4;
            const int p0 = ((c >> 1) & 7) * 128 + (c >> 4) * 2;
            const int p1 = (((c + 2) >> 1) & 7) * 128 + ((c + 2) >> 4) * 2;
            union { f16 h[2]; uint u; } u01, u23;
            u01.h[0] = (f16)v.x; u01.h[1] = (f16)v.y;
            u23.h[0] = (f16)v.z; u23.h[1] = (f16)v.w;
            *(uint*)(d + (size_t)r * 1024 + p0) = u01.u;
            *(uint*)(d + (size_t)r * 1024 + p1) = u23.u;
        }
    }
}

// ---------------- GEMM: C = A(M x K) * B(N x K)^T + bias ----------------
// r5 config (measured 41us QKV, 0 conflicts): 128x64 tile, BK=64, 4 waves
// (2M x 2N), dbuf LDS 48KB + counted vmcnt(6) + both-sides XOR swizzle.
struct GemmArgs {
    const f16*   A[3];
    const f16*   B[3];
    const float* bias[3];
    void*        C[3];
};

#define VM_WAIT6 asm volatile("s_waitcnt vmcnt(6)" ::: "memory")
#define VM_WAIT0 asm volatile("s_waitcnt vmcnt(0)" ::: "memory")

template<int OUTMODE>   // 0 = f16 out + inv-perm bias (QKV), 1 = f32 out direct bias
__global__ __launch_bounds__(256) void gemm_bt_kernel(GemmArgs ga) {
    constexpr int K = KDIM, N = NDIM;
    constexpr int NT = K / 64;           // 16 K-steps
    const f16*   A    = ga.A[blockIdx.z];
    const f16*   B    = ga.B[blockIdx.z];
    const float* bias = ga.bias[blockIdx.z];

    __shared__ f16 sm[2 * (128 * 64 + 64 * 64)];   // 48 KB

    const int tid  = threadIdx.x;
    const int wave = tid >> 6, lane = tid & 63;
    const int wm = wave >> 1, wn = wave & 1;
    const int bm = blockIdx.x * 128, bn = blockIdx.y * 64;
    const int lrow = lane & 15, kgrp = lane >> 4;

    f32x4 acc[4][2] = {};

    const int colL = (lane & 7) << 3;                              // linear LDS col
    const int colG = (((lane & 7) ^ ((lane >> 3) & 7)) << 3);      // pre-swizzled global col
    const int arow = wave * 32 + (lane >> 3);
    const int brow = wave * 16 + (lane >> 3);

    auto stage = [&](int buf, int kt) {
        f16* As = sm + buf * (128 * 64 + 64 * 64);
        f16* Bs = As + 128 * 64;
        #pragma unroll
        for (int i = 0; i < 4; ++i) {
            const int row = arow + i * 8;
            gload_lds16(A + (size_t)(bm + row) * K + kt + colG, As + row * 64 + colL);
        }
        #pragma unroll
        for (int i = 0; i < 2; ++i) {
            const int row = brow + i * 8;
            gload_lds16(B + (size_t)(bn + row) * K + kt + colG, Bs + row * 64 + colL);
        }
    };

    stage(0, 0);

    const int swz = (lrow & 7) << 3;

    for (int it = 0; it < NT; ++it) {
        const int cur = it & 1;
        if (it + 1 < NT) {
            stage(cur ^ 1, (it + 1) * 64);
            VM_WAIT6;
        } else {
            VM_WAIT0;
        }
        __builtin_amdgcn_s_barrier();
        __builtin_amdgcn_sched_barrier(0);

        const f16* As = sm + cur * (128 * 64 + 64 * 64);
        const f16* Bs = As + 128 * 64;
        #pragma unroll
        for (int kk = 0; kk < 2; ++kk) {
            f16x8 af[4], bf[2];
            const int kcol = (kk * 32 + kgrp * 8) ^ swz;
            #pragma unroll
            for (int mi = 0; mi < 4; ++mi)
                af[mi] = *(const f16x8*)(As + (wm * 64 + mi * 16 + lrow) * 64 + kcol);
            #pragma unroll
            for (int ni = 0; ni < 2; ++ni)
                bf[ni] = *(const f16x8*)(Bs + (wn * 32 + ni * 16 + lrow) * 64 + kcol);
            #pragma unroll
            for (int mi = 0; mi < 4; ++mi)
                #pragma unroll
                for (int ni = 0; ni < 2; ++ni)
                    acc[mi][ni] = __builtin_amdgcn_mfma_f32_16x16x32_f16(af[mi], bf[ni], acc[mi][ni], 0, 0, 0);
        }
        __builtin_amdgcn_s_barrier();
    }

    // C/D layout: col = lane&15, row = (lane>>4)*4 + reg  [verified m89/m91]
    const int rbase = kgrp * 4;
    #pragma unroll
    for (int mi = 0; mi < 4; ++mi) {
        #pragma unroll
        for (int ni = 0; ni < 2; ++ni) {
            const int col = bn + wn * 32 + ni * 16 + lrow;
            const int bidx = (OUTMODE == 0)
                ? (((col >> 1) & 63) * 16 + (col >> 7) * 2 + (col & 1))  // invperm
                : col;
            const float bv = bias[bidx];
            #pragma unroll
            for (int r = 0; r < 4; ++r) {
                const int row = bm + wm * 64 + mi * 16 + rbase + r;
                const float v = acc[mi][ni][r] + bv;
                if constexpr (OUTMODE == 0)
                    ((f16*)ga.C[blockIdx.z])[(size_t)row * N + col] = (f16)v;
                else
                    ((float*)ga.C[blockIdx.z])[(size_t)row * N + col] = v;
            }
        }
    }
}

// ---------------- attention over d_keys axis ----------------
// Block = 1 token (512 thr, wave = head, lane = query row l).
// r7 showed global broadcast loads are latency-bound (VALU 40%, time flat).
// Fix: coalesced one-shot LDS stage (k 2KB, v cvt'd to f32 4KB), then each
// wave pulls its head's k/v via uniform-address ds_read_b128 broadcasts
// (12 per 16-s group, conflict-free, latency hidden under 16-iter compute).
// Inner loop: v_dot2_f32_f16 + raw v_exp_f32 + add + v_pk_fma_f32.
__global__ __launch_bounds__(512) void attn_kernel(const f16* qp, const f16* kp,
                                                   const f16* vp, f16* ao) {
    __shared__ __align__(16) uint   kls[512];
    __shared__ __align__(16) f32x2  vls[512];
    const int tid = threadIdx.x, head = tid >> 6, lane = tid & 63;
    const size_t base = (size_t)blockIdx.x * 512;   // token's pair index
    const float SCALE = 0.70710678118f * 1.44269504089f;  // 1/sqrt(2)*log2(e)

    union U2 { uint u; h2 h; f16 s[2]; };
    // coalesced stage: each thread 1 k-uint + 1 v-uint (cvt to f32)
    kls[tid] = ((const uint*)kp)[base + tid];
    U2 vu; vu.u = ((const uint*)vp)[base + tid];
    vls[tid] = (f32x2){(float)vu.s[0], (float)vu.s[1]};

    U2 qu; qu.u = ((const uint*)qp)[base + tid];    // = head*64 + lane
    const float q0 = (float)qu.s[0] * SCALE, q1 = (float)qu.s[1] * SCALE;
#if __has_builtin(__builtin_amdgcn_fdot2)
    h2 qs; qs[0] = (f16)q0; qs[1] = (f16)q1;
#endif
    __syncthreads();

    const u32x4* kb = (const u32x4*)&kls[head * 64];   // 16 x b128
    const f32x4* vb = (const f32x4*)&vls[head * 64];   // 32 x b128

    f32x2 o01 = {0.f, 0.f};
    float sum0 = 0.f, sum1 = 0.f;
    #pragma unroll
    for (int g = 0; g < 4; ++g) {
        u32x4 kr[4];   // 16 k-pairs
        f32x4 vr[8];   // 16 v float2s
        #pragma unroll
        for (int i = 0; i < 4; ++i) kr[i] = kb[g * 4 + i];
        #pragma unroll
        for (int i = 0; i < 8; ++i) vr[i] = vb[g * 8 + i];
        #pragma unroll
        for (int s = 0; s < 16; ++s) {
            U2 ku; ku.u = kr[s >> 2][s & 3];
#if __has_builtin(__builtin_amdgcn_fdot2)
            const float sc = __builtin_amdgcn_fdot2(qs, ku.h, 0.0f, false);
#else
            const float sc = fmaf(q0, (float)ku.s[0], q1 * (float)ku.s[1]);
#endif
            const float p = EXP2(sc);
            if (s & 1) sum1 += p; else sum0 += p;
            const f32x2 v2 = {vr[s >> 1][(s & 1) << 1], vr[s >> 1][((s & 1) << 1) + 1]};
            o01 = __builtin_elementwise_fma((f32x2){p, p}, v2, o01);
        }
    }
    const float inv = __builtin_amdgcn_rcpf(sum0 + sum1);
    U2 o;
    o.s[0] = (f16)(o01.x * inv);
    o.s[1] = (f16)(o01.y * inv);
    ((uint*)ao)[base + tid] = o.u;
}

// ---------------- launch ----------------
extern "C" void kernel_launch(void* const* d_in, const int* in_sizes, int n_in,
                              void* d_out, int out_size, void* d_ws, size_t ws_size,
                              hipStream_t stream) {
    const float* queries = (const float*)d_in[0];
    const float* keys    = (const float*)d_in[1];
    const float* values  = (const float*)d_in[2];
    const float* Wq = (const float*)d_in[3];
    const float* bq = (const float*)d_in[4];
    const float* Wk = (const float*)d_in[5];
    const float* bk = (const float*)d_in[6];
    const float* Wv = (const float*)d_in[7];
    const float* bv = (const float*)d_in[8];
    const float* Wo = (const float*)d_in[9];
    const float* bo = (const float*)d_in[10];

    char* ws = (char*)d_ws;
    const size_t MB = 1024 * 1024;
    f16* Xq  = (f16*)(ws + 0 * MB);    // 4096x1024 f16 = 8 MB
    f16* Xk  = (f16*)(ws + 8 * MB);
    f16* Xv  = (f16*)(ws + 16 * MB);
    f16* Wqh = (f16*)(ws + 24 * MB);   // row-permuted, 2 MB
    f16* Wkh = (f16*)(ws + 26 * MB);
    f16* Wvh = (f16*)(ws + 28 * MB);
    f16* Woh = (f16*)(ws + 30 * MB);   // col-permuted
    f16* qp  = (f16*)(ws + 32 * MB);   // [token][head][d] packed, 8 MB each
    f16* kp  = (f16*)(ws + 40 * MB);
    f16* vp  = (f16*)(ws + 48 * MB);
    f16* ao  = (f16*)(ws + 56 * MB);

    CvtArgs ca;
    ca.src[0] = queries; ca.dst[0] = Xq;  ca.n4[0] = TOK * KDIM / 4;  ca.type[0] = 0;
    ca.src[1] = keys;    ca.dst[1] = Xk;  ca.n4[1] = TOK * KDIM / 4;  ca.type[1] = 0;
    ca.src[2] = values;  ca.dst[2] = Xv;  ca.n4[2] = TOK * KDIM / 4;  ca.type[2] = 0;
    ca.src[3] = Wq;      ca.dst[3] = Wqh; ca.n4[3] = NDIM * KDIM / 4; ca.type[3] = 1;
    ca.src[4] = Wk;      ca.dst[4] = Wkh; ca.n4[4] = NDIM * KDIM / 4; ca.type[4] = 1;
    ca.src[5] = Wv;      ca.dst[5] = Wvh; ca.n4[5] = NDIM * KDIM / 4; ca.type[5] = 1;
    ca.src[6] = Wo;      ca.dst[6] = Woh; ca.n4[6] = NDIM * KDIM / 4; ca.type[6] = 2;
    cvt_kernel<<<dim3(256, 7), 256, 0, stream>>>(ca);

    GemmArgs g1;
    g1.A[0] = Xq;  g1.A[1] = Xk;  g1.A[2] = Xv;
    g1.B[0] = Wqh; g1.B[1] = Wkh; g1.B[2] = Wvh;
    g1.bias[0] = bq; g1.bias[1] = bk; g1.bias[2] = bv;
    g1.C[0] = qp; g1.C[1] = kp; g1.C[2] = vp;
    gemm_bt_kernel<0><<<dim3(32, 16, 3), 256, 0, stream>>>(g1);

    attn_kernel<<<TOK, 512, 0, stream>>>(qp, kp, vp, ao);

    GemmArgs g2;
    g2.A[0] = ao; g2.B[0] = Woh; g2.bias[0] = bo; g2.C[0] = d_out;
    g2.A[1] = ao; g2.B[1] = Woh; g2.bias[1] = bo; g2.C[1] = d_out;  // unused slots
    g2.A[2] = ao; g2.B[2] = Woh; g2.bias[2] = bo; g2.C[2] = d_out;
    gemm_bt_kernel<1><<<dim3(32, 16, 1), 256, 0, stream>>>(g2);
}